// Round 6
// baseline (244.258 us; speedup 1.0000x reference)
//
#include <hip/hip_runtime.h>
#include <stdint.h>

// LIF scan: u = 0.5*u + x_t; o = (u > 1); u = 0 where spiked. Bit-exact.
// x: [B=32, T=128, N=8192] fp32; out same, values in {0,1}.
//
// R13: DRAM-granularity experiment. R10/R11/R12 (and the R7 LDS ring) are
// four different structures that all land at 75+-6us ~= 3.3 TB/s vs the
// 6.3 TB/s linear-copy ceiling. Shared invariant: every t-step touches only
// 1 KB contiguous per block (32 KB stride) on both reads and stores ->
// DRAM page/channel locality loss. R12's store-free scan refuted the
// vmcnt-poisoning theory; this round tests granularity:
//   1024-thread blocks, 1 scalar chain/thread -> 4 KB contiguous per block
//   per t-step (4x R12) at IDENTICAL occupancy (256 blocks = 1/CU,
//   16 waves/CU = 4/SIMD). Default dispatch spreads the 8 segments of each
//   b-row across the 8 XCDs -> device sweeps whole 1-MB t-rows near-linearly.
//   Raw s_barrier (builtin, NO memory semantics -> no vmcnt(0) drain, the
//   R1-R6 trap) every 16 steps keeps the 16 waves t-aligned so the 4-KB
//   chunks stay temporally contiguous.
// Scan is store-free (spikes bit-packed in 4 u32), burst store is nt.
// If this is still ~80us, granularity is refuted at 4-KB scale and the
// ~75us plateau is the pattern-level roofline.

constexpr int B  = 32;
constexpr int T  = 128;
constexpr int N  = 8192;
constexpr int THREADS = 1024;
constexpr int NSEG    = N / THREADS;   // 8 segments per batch row
constexpr int DP      = 16;            // load pipeline depth in t-steps

__global__ __launch_bounds__(THREADS) void lif_kernel(const float* __restrict__ x,
                                                      float* __restrict__ out) {
    const int tid  = threadIdx.x;
    const int b    = blockIdx.x >> 3;              // NSEG = 8
    const int seg  = blockIdx.x & (NSEG - 1);
    const uint32_t base = (uint32_t)b * (T * N) + (uint32_t)seg * THREADS + tid;
    const float* gx = x + base;                    // stride N floats per t
    float*       go = out + base;

    // prologue: fill the 16-deep pipe (16 independent dword loads in flight)
    float pipe[DP];
    #pragma unroll
    for (int k = 0; k < DP; ++k) pipe[k] = gx[(uint32_t)k * N];

    float u = 0.f;
    uint32_t sw0 = 0u, sw1 = 0u, sw2 = 0u, sw3 = 0u;   // 128 spike bits

    // scan: pure load stream, fully unrolled (static pipe indices).
    #pragma unroll
    for (int t = 0; t < T; ++t) {
        // keep the block's 16 waves t-aligned; raw barrier, no vmcnt drain
        if ((t & 15) == 0) __builtin_amdgcn_s_barrier();
        const float v = pipe[t & (DP - 1)];
        if (t + DP < T)
            pipe[t & (DP - 1)] = gx[(uint32_t)(t + DP) * N];  // prefetch t+DP
        u = 0.5f * u + v;                       // bit-exact leak+integrate
        const bool s = u > 1.0f;
        const uint32_t bit = s ? 1u : 0u;
        if      (t <  32) sw0 |= bit << t;
        else if (t <  64) sw1 |= bit << (t - 32);
        else if (t <  96) sw2 |= bit << (t - 64);
        else              sw3 |= bit << (t - 96);
        u = s ? 0.0f : u;                       // hard reset
    }

    // burst: 128 nt stores, 4 KB contiguous per block per t (waves aligned
    // by the final scan barrier epoch).
    #pragma unroll
    for (int t = 0; t < T; ++t) {
        const uint32_t w = (t < 32) ? sw0 : (t < 64) ? sw1 : (t < 96) ? sw2 : sw3;
        const float sp = ((w >> (t & 31)) & 1u) ? 1.0f : 0.0f;
        __builtin_nontemporal_store(sp, go + (uint32_t)t * N);
    }
}

extern "C" void kernel_launch(void* const* d_in, const int* in_sizes, int n_in,
                              void* d_out, int out_size, void* d_ws, size_t ws_size,
                              hipStream_t stream) {
    const float* x   = (const float*)d_in[0];
    float*       out = (float*)d_out;
    lif_kernel<<<B * NSEG, THREADS, 0, stream>>>(x, out);   // 256 blocks, 1/CU
}

// Round 7
// 241.214 us; speedup vs baseline: 1.0126x; 1.0126x over previous
//
#include <hip/hip_runtime.h>
#include <stdint.h>

// LIF scan: u = 0.5*u + x_t; o = (u > 1); u = 0 where spiked. Bit-exact.
// x: [B=32, T=128, N=8192] fp32; out same, values in {0,1}.
//
// R14: split read-scan and write-expand into two kernels.
// Ledger: R7 ring ~70us, R10 ~81, R11 ~74, R12 ~81, R13 ~100. All share one
// thing: a concurrent 131MB strided write stream during the scan. R13's
// counters: FETCH=70MB (half the input LLC-resident), per-CU service 6.25
// B/cyc vs copy's 10. In-flight bytes are 2.5x the BW-delay product -> not
// latency. Mechanism: the write stream flows through the memory-side LLC,
// evicting the 128MB input (131MB writes / 256MB LLC -> ~50% input survival
// == observed FETCH), and forces R/W interleave at DRAM.
// Fix: a chain's 128 spikes = 4 u32 = one dwordx4.
//   K1 scan: R12 structure, stores only 4MB bit-packed (cached, coalesced).
//            No write stream -> input stays LLC-resident, reads go fast.
//   K2 expand: block owns [b, 4 t-rows, all n] = 128KB CONTIGUOUS output,
//            reads packed bits (4MB, LLC-hot), writes 131MB fully linear nt
//            (the fill kernel proves 6.7 TB/s for exactly this pattern).
// No LDS, no barriers in either kernel. Fallback to single-kernel R12 path
// if workspace < 4MB.

constexpr int B  = 32;
constexpr int T  = 128;
constexpr int N  = 8192;
constexpr int THREADS = 256;
constexpr int NTILES  = N / THREADS;   // 32 n-tiles per batch row
constexpr int DP      = 16;            // load pipeline depth in t-steps
constexpr size_t WS_NEEDED = (size_t)B * N * 16;   // 4 MiB packed spikes

// ---------------- K1: scan, bit-packed output (4 MB) ----------------
__global__ __launch_bounds__(THREADS) void scan_kernel(const float* __restrict__ x,
                                                       uint4* __restrict__ ws4) {
    const int tid   = threadIdx.x;
    const int b     = blockIdx.x >> 5;              // NTILES = 32
    const int ntile = blockIdx.x & (NTILES - 1);
    const uint32_t base = (uint32_t)b * (T * N) + (uint32_t)ntile * THREADS + tid;
    const float* gx = x + base;                     // stride N floats per t

    float pipe[DP];
    #pragma unroll
    for (int k = 0; k < DP; ++k) pipe[k] = gx[(uint32_t)k * N];

    float u = 0.f;
    uint32_t sw0 = 0u, sw1 = 0u, sw2 = 0u, sw3 = 0u;

    #pragma unroll
    for (int t = 0; t < T; ++t) {
        const float v = pipe[t & (DP - 1)];
        if (t + DP < T)
            pipe[t & (DP - 1)] = gx[(uint32_t)(t + DP) * N];  // prefetch t+DP
        u = 0.5f * u + v;
        const bool s = u > 1.0f;
        const uint32_t bit = s ? 1u : 0u;
        if      (t <  32) sw0 |= bit << t;
        else if (t <  64) sw1 |= bit << (t - 32);
        else if (t <  96) sw2 |= bit << (t - 64);
        else              sw3 |= bit << (t - 96);
        u = s ? 0.0f : u;
    }

    // one coalesced dwordx4 per thread; cached (K2 reads it through LLC)
    const uint32_t chain = (uint32_t)b * N + (uint32_t)ntile * THREADS + tid;
    ws4[chain] = make_uint4(sw0, sw1, sw2, sw3);
}

// ---------------- K2: expand packed bits -> linear 131 MB ----------------
__global__ __launch_bounds__(THREADS) void expand_kernel(const uint4* __restrict__ ws4,
                                                         float* __restrict__ out) {
    const int tid = threadIdx.x;
    const int b   = blockIdx.x >> 5;               // 32 t-groups per b
    const int tg  = blockIdx.x & 31;               // 4 t-rows per group
    const uint4* src = ws4 + (uint32_t)b * N;
    float* dst = out + (size_t)b * (T * N) + (size_t)tg * 4 * N;
    const int w  = tg >> 3;                        // which packed word
    const int s0 = (tg & 7) * 4;                   // bit base within word

    // stage the 32 relevant words in regs (static indices; ~32 VGPR)
    uint32_t pw[32];
    #pragma unroll
    for (int i = 0; i < 32; ++i) {
        const uint4 p = src[(uint32_t)i * THREADS + tid];
        pw[i] = (w == 0) ? p.x : (w == 1) ? p.y : (w == 2) ? p.z : p.w;
    }

    // 4 rows, each written start-to-end linearly (1 KB/wave-instr, dense
    // 32 KB sweep per row); nt keeps the write stream out of the LLC.
    #pragma unroll
    for (int dt = 0; dt < 4; ++dt) {
        float* row = dst + (size_t)dt * N;
        #pragma unroll
        for (int i = 0; i < 32; ++i) {
            const float f = ((pw[i] >> (s0 + dt)) & 1u) ? 1.0f : 0.0f;
            __builtin_nontemporal_store(f, row + (uint32_t)i * THREADS + tid);
        }
    }
}

// ---------------- fallback: R12 single-kernel (no workspace) ----------------
__global__ __launch_bounds__(THREADS) void lif_kernel(const float* __restrict__ x,
                                                      float* __restrict__ out) {
    const int tid   = threadIdx.x;
    const int b     = blockIdx.x >> 5;
    const int ntile = blockIdx.x & (NTILES - 1);
    const uint32_t base = (uint32_t)b * (T * N) + (uint32_t)ntile * THREADS + tid;
    const float* gx = x + base;
    float*       go = out + base;

    float pipe[DP];
    #pragma unroll
    for (int k = 0; k < DP; ++k) pipe[k] = gx[(uint32_t)k * N];

    float u = 0.f;
    uint32_t sw0 = 0u, sw1 = 0u, sw2 = 0u, sw3 = 0u;

    #pragma unroll
    for (int t = 0; t < T; ++t) {
        const float v = pipe[t & (DP - 1)];
        if (t + DP < T)
            pipe[t & (DP - 1)] = gx[(uint32_t)(t + DP) * N];
        u = 0.5f * u + v;
        const bool s = u > 1.0f;
        const uint32_t bit = s ? 1u : 0u;
        if      (t <  32) sw0 |= bit << t;
        else if (t <  64) sw1 |= bit << (t - 32);
        else if (t <  96) sw2 |= bit << (t - 64);
        else              sw3 |= bit << (t - 96);
        u = s ? 0.0f : u;
    }

    #pragma unroll
    for (int t = 0; t < T; ++t) {
        const uint32_t wd = (t < 32) ? sw0 : (t < 64) ? sw1 : (t < 96) ? sw2 : sw3;
        const float sp = ((wd >> (t & 31)) & 1u) ? 1.0f : 0.0f;
        __builtin_nontemporal_store(sp, go + (uint32_t)t * N);
    }
}

extern "C" void kernel_launch(void* const* d_in, const int* in_sizes, int n_in,
                              void* d_out, int out_size, void* d_ws, size_t ws_size,
                              hipStream_t stream) {
    const float* x   = (const float*)d_in[0];
    float*       out = (float*)d_out;
    const int nblocks = B * NTILES;                // 1024
    if (d_ws != nullptr && ws_size >= WS_NEEDED) {
        uint4* ws4 = (uint4*)d_ws;
        scan_kernel<<<nblocks, THREADS, 0, stream>>>(x, ws4);
        expand_kernel<<<nblocks, THREADS, 0, stream>>>(ws4, out);
    } else {
        lif_kernel<<<nblocks, THREADS, 0, stream>>>(x, out);
    }
}

// Round 8
// 235.386 us; speedup vs baseline: 1.0377x; 1.0248x over previous
//
#include <hip/hip_runtime.h>
#include <stdint.h>

// LIF scan: u = 0.5*u + x_t; o = (u > 1); u = 0 where spiked. Bit-exact.
// x: [B=32, T=128, N=8192] fp32; out same, values in {0,1}.
//
// R15: R11 (best non-LDS variant, ~74us) + XCD-slab swizzle. Single-variable
// A/B against R11.
// Ledger: R7 ring 70, R10 float4 81, R11 scalar-interleave 74, R12 burst 81,
// R13 1-block/CU 100, R14 split ~89. Write-eviction refuted (R14: pure-read
// scan still ~2.3 TB/s). Remaining untested mechanism: device-wide request
// ordering. Default round-robin dispatch gives XCD k the ntile%8==k chunks:
// every L2 issues isolated 1KB reads scattered over the full 128MB at 32KB
// stride, 8 XCDs interleaving on the same DRAM pages -> max page thrash,
// while linear sweeps (fill kernel) hit 6.7 TB/s.
// Fix: each XCD owns 4 consecutive batches = one CONTIGUOUS 16MB slab.
// xcd = bid&7 (round-robin dispatch, m09/T1); j = bid>>3;
// b = xcd*4 + (j>>5); ntile = j&31. Its 128 blocks cover complete 32KB
// t-rows -> each L2 issues dense sequential spans in its private slab.
// Everything else byte-identical to R11: scalar dword loads (256B/wave),
// 16-deep register pipe, interleaved nt stores, no LDS, no barriers,
// 1024 blocks x 256 thr = 16 waves/CU.
// If lif is unchanged (+-3us): locality refuted too -> pattern roofline,
// declare <<ROOFLINE>> next round.

constexpr int B  = 32;
constexpr int T  = 128;
constexpr int N  = 8192;
constexpr int THREADS = 256;
constexpr int NTILES  = N / THREADS;   // 32 n-tiles per batch row
constexpr int DP      = 16;            // pipeline depth in t-steps
constexpr int NG      = T / DP;        // 8 groups

__global__ __launch_bounds__(THREADS) void lif_kernel(const float* __restrict__ x,
                                                      float* __restrict__ out) {
    const int tid = threadIdx.x;
    // XCD-slab swizzle (round-robin dispatch: xcd = blockIdx % 8)
    const int bid   = blockIdx.x;
    const int xcd   = bid & 7;
    const int j     = bid >> 3;                    // 0..127 within XCD
    const int b     = (xcd << 2) | (j >> 5);       // 4 consecutive b per XCD
    const int ntile = j & 31;
    const uint32_t base = (uint32_t)b * (T * N) + (uint32_t)ntile * THREADS + tid;
    const float* gx = x + base;                    // stride N floats per t
    float*       go = out + base;

    // prologue: fill the 16-deep pipe (16 independent dword loads in flight)
    float pipe[DP];
    #pragma unroll
    for (int k = 0; k < DP; ++k) pipe[k] = gx[(uint32_t)k * N];

    float u = 0.f;

    // main: consume pipe[k] for t=g*DP+k, immediately refill with t+DP.
    #pragma unroll 1
    for (int g = 0; g < NG - 1; ++g) {
        const uint32_t roff = (uint32_t)(g + 1) * (DP * N);
        const uint32_t woff = (uint32_t)g * (DP * N);
        #pragma unroll
        for (int k = 0; k < DP; ++k) {
            const float v = pipe[k];
            pipe[k] = gx[roff + (uint32_t)k * N];   // prefetch t + DP
            u = 0.5f * u + v;                       // bit-exact leak+integrate
            const bool s = u > 1.0f;
            __builtin_nontemporal_store(s ? 1.0f : 0.0f,
                                        go + woff + (uint32_t)k * N);
            u = s ? 0.0f : u;                       // hard reset
        }
    }

    // epilogue group: no prefetch
    {
        const uint32_t woff = (uint32_t)(NG - 1) * (DP * N);
        #pragma unroll
        for (int k = 0; k < DP; ++k) {
            const float v = pipe[k];
            u = 0.5f * u + v;
            const bool s = u > 1.0f;
            __builtin_nontemporal_store(s ? 1.0f : 0.0f,
                                        go + woff + (uint32_t)k * N);
            u = s ? 0.0f : u;
        }
    }
}

extern "C" void kernel_launch(void* const* d_in, const int* in_sizes, int n_in,
                              void* d_out, int out_size, void* d_ws, size_t ws_size,
                              hipStream_t stream) {
    const float* x   = (const float*)d_in[0];
    float*       out = (float*)d_out;
    lif_kernel<<<B * NTILES, THREADS, 0, stream>>>(x, out);   // 1024 blocks
}

// Round 9
// 231.405 us; speedup vs baseline: 1.0555x; 1.0172x over previous
//
#include <hip/hip_runtime.h>
#include <stdint.h>

// LIF scan: u = 0.5*u + x_t; o = (u > 1); u = 0 where spiked. Bit-exact.
// x: [B=32, T=128, N=8192] fp32; out same, values in {0,1}.
//
// R16: in-flight-bytes experiment. R12 structure (store-free scan window,
// bitpacked burst store, no LDS/barriers, 1024x256, direct-measured 80.9us)
// with ONE change: DP 16 -> 32.
// Rationale: refuted so far -- pipeline shape, occupancy (4->16 w/CU),
// store interleave, write-driven LLC eviction, DRAM granularity (256B->4KB),
// XCD slab locality. Never isolated: in-flight read bytes/CU. R7 (only
// sub-75us point) had ~96KB/CU via global_load_lds; all scalar versions
// have 64KB/CU. Fill-rate arithmetic (25 GB/s/CU at 2-3us loaded latency)
// wants 50-75+KB of reads in flight -- we sit at the edge. DP=32 doubles
// to 128KB/CU: 32 outstanding loads/wave (<63 vmcnt max), pipe in VGPRs
// (~50 total, <=64 -> occupancy unchanged at 16 waves/CU).
// Predict: lever real -> 58-66us. Unchanged -> pattern-level HW ceiling
// (~2.5 TB/s for 32KB-strided row sweeps), declare ROOFLINE.

constexpr int B  = 32;
constexpr int T  = 128;
constexpr int N  = 8192;
constexpr int THREADS = 256;
constexpr int NTILES  = N / THREADS;   // 32 n-tiles per batch row
constexpr int DP      = 32;            // load pipeline depth in t-steps

__global__ __launch_bounds__(THREADS) void lif_kernel(const float* __restrict__ x,
                                                      float* __restrict__ out) {
    const int tid   = threadIdx.x;
    const int b     = blockIdx.x >> 5;              // NTILES = 32
    const int ntile = blockIdx.x & (NTILES - 1);
    const uint32_t base = (uint32_t)b * (T * N) + (uint32_t)ntile * THREADS + tid;
    const float* gx = x + base;                     // stride N floats per t
    float*       go = out + base;

    // prologue: fill the 32-deep pipe (32 independent dword loads in flight)
    float pipe[DP];
    #pragma unroll
    for (int k = 0; k < DP; ++k) pipe[k] = gx[(uint32_t)k * N];

    float u = 0.f;
    uint32_t sw0 = 0u, sw1 = 0u, sw2 = 0u, sw3 = 0u;   // 128 spike bits

    // scan: pure load stream -- no stores in the vmcnt window. Fully
    // unrolled so pipe[] indices and sw selects are compile-time static.
    #pragma unroll
    for (int t = 0; t < T; ++t) {
        const float v = pipe[t & (DP - 1)];
        if (t + DP < T)
            pipe[t & (DP - 1)] = gx[(uint32_t)(t + DP) * N];  // prefetch t+DP
        u = 0.5f * u + v;                       // bit-exact leak+integrate
        const bool s = u > 1.0f;
        const uint32_t bit = s ? 1u : 0u;
        if      (t <  32) sw0 |= bit << t;
        else if (t <  64) sw1 |= bit << (t - 32);
        else if (t <  96) sw2 |= bit << (t - 64);
        else              sw3 |= bit << (t - 96);
        u = s ? 0.0f : u;                       // hard reset
    }

    // burst: 128 independent coalesced nt stores (1 KB/wave-instr).
    #pragma unroll
    for (int t = 0; t < T; ++t) {
        const uint32_t w = (t < 32) ? sw0 : (t < 64) ? sw1 : (t < 96) ? sw2 : sw3;
        const float sp = ((w >> (t & 31)) & 1u) ? 1.0f : 0.0f;
        __builtin_nontemporal_store(sp, go + (uint32_t)t * N);
    }
}

extern "C" void kernel_launch(void* const* d_in, const int* in_sizes, int n_in,
                              void* d_out, int out_size, void* d_ws, size_t ws_size,
                              hipStream_t stream) {
    const float* x   = (const float*)d_in[0];
    float*       out = (float*)d_out;
    lif_kernel<<<B * NTILES, THREADS, 0, stream>>>(x, out);   // 1024 blocks
}